// Round 5
// baseline (391.127 us; speedup 1.0000x reference)
//
#include <hip/hip_runtime.h>
#include <math.h>

// ---------- sizes (compile-time for this problem) ----------
#define B_  2
#define S_  512
#define P_  4096
#define TD_ 512
#define SD_ 384
#define H_  8
#define HD_ 64
#define FF_ 2048

typedef _Float16 half8 __attribute__((ext_vector_type(8)));
typedef _Float16 half4 __attribute__((ext_vector_type(4)));
typedef float floatx4 __attribute__((ext_vector_type(4)));

// ---------------- block reduction (sum of two values) ----------------
__device__ __forceinline__ float2 block_sum2(float a, float b) {
    for (int off = 32; off > 0; off >>= 1) {
        a += __shfl_down(a, off);
        b += __shfl_down(b, off);
    }
    __shared__ float sa[8], sb[8];
    int w = threadIdx.x >> 6;
    if ((threadIdx.x & 63) == 0) { sa[w] = a; sb[w] = b; }
    __syncthreads();
    int nw = blockDim.x >> 6;
    float ta = 0.f, tb = 0.f;
    for (int i = 0; i < nw; ++i) { ta += sa[i]; tb += sb[i]; }
    __syncthreads();
    return make_float2(ta, tb);
}

// ---------------- prep: 6 weight transposes + both input LayerNorms, ONE launch ----------------
__global__ __launch_bounds__(256) void prep_kernel(
    const float* __restrict__ s0p, const float* __restrict__ s1p,
    const float* __restrict__ s2p, const float* __restrict__ s3p,
    const float* __restrict__ s4p, const float* __restrict__ s5p,
    _Float16* __restrict__ d0p, _Float16* __restrict__ d1p,
    _Float16* __restrict__ d2p, _Float16* __restrict__ d3p,
    _Float16* __restrict__ d4p, _Float16* __restrict__ d5p,
    const float* __restrict__ text, const float* __restrict__ shape,
    const float* __restrict__ tn_g, const float* __restrict__ tn_b,
    const float* __restrict__ sn_g, const float* __restrict__ sn_b,
    _Float16* __restrict__ tn_h, _Float16* __restrict__ sn_h)
{
    __shared__ float ts[32][33];
    int id = blockIdx.x;
    int tid = threadIdx.x;
    if (id < 2944) {
        const float* src; _Float16* dst; int K, N, t, nlog;
        if (id < 256)       { src=s0p; dst=d0p; K=512;  N=512;  t=id;       nlog=4; }  // Wq
        else if (id < 448)  { src=s1p; dst=d1p; K=384;  N=512;  t=id-256;   nlog=4; }  // Wk
        else if (id < 640)  { src=s2p; dst=d2p; K=384;  N=512;  t=id-448;   nlog=4; }  // Wv
        else if (id < 896)  { src=s3p; dst=d3p; K=512;  N=512;  t=id-640;   nlog=4; }  // Wo
        else if (id < 1920) { src=s4p; dst=d4p; K=512;  N=2048; t=id-896;   nlog=6; }  // W1
        else                { src=s5p; dst=d5p; K=2048; N=512;  t=id-1920;  nlog=4; }  // W2
        int n0 = (t & ((1 << nlog) - 1)) << 5;
        int k0 = (t >> nlog) << 5;
#pragma unroll
        for (int i = 0; i < 4; ++i) {
            int e = i * 256 + tid;
            int kk = e >> 5, nn = e & 31;
            ts[kk][nn] = src[(size_t)(k0 + kk) * N + n0 + nn];
        }
        __syncthreads();
#pragma unroll
        for (int i = 0; i < 4; ++i) {
            int e = i * 256 + tid;
            int nn = e >> 5, kk = e & 31;
            dst[(size_t)(n0 + nn) * K + k0 + kk] = (_Float16)ts[kk][nn];
        }
        return;
    }
    int row = id - 2944;
    const float* xr; const float* g; const float* be; _Float16* yr; int D;
    if (row < 1024) {
        D = 512; xr = text + (size_t)row * 512; g = tn_g; be = tn_b;
        yr = tn_h + (size_t)row * 512;
    } else {
        int r2 = row - 1024;
        D = 384; xr = shape + (size_t)r2 * 384; g = sn_g; be = sn_b;
        yr = sn_h + (size_t)r2 * 384;
    }
    float s = 0.f, s2 = 0.f;
    for (int i = tid; i < D; i += 256) {
        float v = xr[i]; s += v; s2 += v * v;
    }
    float2 r = block_sum2(s, s2);
    float mean = r.x / (float)D;
    float var  = r.y / (float)D - mean * mean;
    float rstd = rsqrtf(var + 1e-5f);
    for (int i = tid; i < D; i += 256)
        yr[i] = (_Float16)((xr[i] - mean) * rstd * g[i] + be[i]);
}

// ---------------- LN (D=512): (f32 a + sum of np f32 partials) -> f32 and/or f16 out ----------------
__global__ __launch_bounds__(256) void ln_add_kernel(
    const float* __restrict__ a, const float* __restrict__ c, int np, int cstride,
    const float* __restrict__ g, const float* __restrict__ be,
    float* __restrict__ yf, _Float16* __restrict__ yh)
{
    int row = blockIdx.x;
    int i0 = threadIdx.x, i1 = threadIdx.x + 256;
    const float* ar = a + (size_t)row * 512;
    const float* cr = c + (size_t)row * 512;
    float v0 = ar[i0], v1 = ar[i1];
    for (int t = 0; t < np; ++t) {
        v0 += cr[(size_t)t * cstride + i0];
        v1 += cr[(size_t)t * cstride + i1];
    }
    float2 rd = block_sum2(v0 + v1, v0 * v0 + v1 * v1);
    float mean = rd.x / 512.f;
    float var  = rd.y / 512.f - mean * mean;
    float rstd = rsqrtf(var + 1e-5f);
    float o0 = (v0 - mean) * rstd * g[i0] + be[i0];
    float o1 = (v1 - mean) * rstd * g[i1] + be[i1];
    if (yf) { yf[(size_t)row * 512 + i0] = o0; yf[(size_t)row * 512 + i1] = o1; }
    if (yh) { yh[(size_t)row * 512 + i0] = (_Float16)o0; yh[(size_t)row * 512 + i1] = (_Float16)o1; }
}

// ---------------- MFMA GEMM: C[M,N] = A[M,K] @ Bt[N,K]^T + bias (tail GEMMs) ----------------
// 128x128 tile, BK=32, 4 waves each 64x64. T14 prefetch.
// ACT: 1=gelu. OUTF: write f32 C (at split offset). OUTH: write f16 C.
// SPLITK: blockIdx.z splits K; bias added only by split 0; f32 partials summed later.
template<int ACT, int OUTF, int OUTH, int SPLITK>
__global__ __launch_bounds__(256) void gemm_f16_kernel(
    const _Float16* __restrict__ A, const _Float16* __restrict__ Bt,
    const float* __restrict__ bias, float* __restrict__ Cf,
    _Float16* __restrict__ Ch, int M, int N, int K)
{
    __shared__ _Float16 As[128 * 40];
    __shared__ _Float16 Bs[128 * 40];
    int tid = threadIdx.x;
    int bm = blockIdx.y * 128, bn = blockIdx.x * 128;
    int wave = tid >> 6, lane = tid & 63, quad = lane >> 4, r = lane & 15;
    int mh = (wave & 1) * 64, nh = (wave >> 1) * 64;

    floatx4 acc[4][4];
    floatx4 zz = {0.f, 0.f, 0.f, 0.f};
#pragma unroll
    for (int i = 0; i < 4; ++i)
#pragma unroll
        for (int j = 0; j < 4; ++j) acc[i][j] = zz;

    int srow = tid >> 2;          // 0..63
    int sko  = (tid & 3) * 8;     // 0,8,16,24

    int ksplit = (SPLITK > 1) ? blockIdx.z : 0;
    int kbeg = ksplit * (K / SPLITK);
    int kend = kbeg + K / SPLITK;

    const _Float16* Ap0 = A  + (size_t)(bm + srow) * K + sko;
    const _Float16* Ap1 = A  + (size_t)(bm + srow + 64) * K + sko;
    const _Float16* Bp0 = Bt + (size_t)(bn + srow) * K + sko;
    const _Float16* Bp1 = Bt + (size_t)(bn + srow + 64) * K + sko;

    half8 ra0 = *(const half8*)(Ap0 + kbeg);
    half8 ra1 = *(const half8*)(Ap1 + kbeg);
    half8 rb0 = *(const half8*)(Bp0 + kbeg);
    half8 rb1 = *(const half8*)(Bp1 + kbeg);

    for (int k0 = kbeg; k0 < kend; k0 += 32) {
        *(half8*)&As[srow * 40 + sko]        = ra0;
        *(half8*)&As[(srow + 64) * 40 + sko] = ra1;
        *(half8*)&Bs[srow * 40 + sko]        = rb0;
        *(half8*)&Bs[(srow + 64) * 40 + sko] = rb1;
        __syncthreads();
        if (k0 + 32 < kend) {
            ra0 = *(const half8*)(Ap0 + k0 + 32);
            ra1 = *(const half8*)(Ap1 + k0 + 32);
            rb0 = *(const half8*)(Bp0 + k0 + 32);
            rb1 = *(const half8*)(Bp1 + k0 + 32);
        }
        half8 af[4], bf[4];
#pragma unroll
        for (int t = 0; t < 4; ++t) {
            af[t] = *(const half8*)&As[(mh + t * 16 + r) * 40 + quad * 8];
            bf[t] = *(const half8*)&Bs[(nh + t * 16 + r) * 40 + quad * 8];
        }
#pragma unroll
        for (int i = 0; i < 4; ++i)
#pragma unroll
            for (int j = 0; j < 4; ++j)
                acc[i][j] = __builtin_amdgcn_mfma_f32_16x16x32_f16(af[i], bf[j], acc[i][j], 0, 0, 0);
        __syncthreads();
    }

#pragma unroll
    for (int j = 0; j < 4; ++j) {
        int col = bn + nh + j * 16 + r;
        float bv = (SPLITK == 1 || ksplit == 0) ? bias[col] : 0.f;
#pragma unroll
        for (int i = 0; i < 4; ++i) {
#pragma unroll
            for (int g = 0; g < 4; ++g) {
                int row = bm + mh + i * 16 + quad * 4 + g;
                float v = acc[i][j][g] + bv;
                if (ACT) v = 0.5f * v * (1.0f + erff(v * 0.70710678118654752f));
                if (OUTF) Cf[(size_t)ksplit * M * N + (size_t)row * N + col] = v;
                if (OUTH) Ch[(size_t)row * N + col] = (_Float16)v;
            }
        }
    }
}

// ---------------- fused Q/K/V projection, 256x128 tiles, 512 threads ----------------
// grid (4, 68): y<4 -> Q (M=1024,K=512); y<36 -> K (M=8192,K=384); else V (scatter to Vt).
// 8 waves laid 4m x 2n, each 64x64 (4x4 MFMA). B-tile shared across 256 A-rows.
__global__ __launch_bounds__(512) void qkv_gemm_kernel(
    const _Float16* __restrict__ tn, const _Float16* __restrict__ sn,
    const _Float16* __restrict__ Wqt, const _Float16* __restrict__ Wkt,
    const _Float16* __restrict__ Wvt,
    const float* __restrict__ bq, const float* __restrict__ bk,
    const float* __restrict__ bv,
    _Float16* __restrict__ Qh, _Float16* __restrict__ Kh, _Float16* __restrict__ Vth)
{
    __shared__ _Float16 As[256 * 40];
    __shared__ _Float16 Bs[128 * 40];
    int by = blockIdx.y;
    const _Float16* A; const _Float16* Bt; const float* bias; _Float16* out;
    int K, bm, vt;
    if (by < 4)       { A = tn; Bt = Wqt; bias = bq; K = 512; bm = by * 256;        vt = 0; out = Qh;  }
    else if (by < 36) { A = sn; Bt = Wkt; bias = bk; K = 384; bm = (by - 4) * 256;  vt = 0; out = Kh;  }
    else              { A = sn; Bt = Wvt; bias = bv; K = 384; bm = (by - 36) * 256; vt = 1; out = Vth; }
    int bn = blockIdx.x * 128;
    int tid = threadIdx.x;
    int wave = tid >> 6, lane = tid & 63, quad = lane >> 4, r = lane & 15;
    int mh = (wave >> 1) * 64, nh = (wave & 1) * 64;

    floatx4 acc[4][4];
    floatx4 zz = {0.f, 0.f, 0.f, 0.f};
#pragma unroll
    for (int i = 0; i < 4; ++i)
#pragma unroll
        for (int j = 0; j < 4; ++j) acc[i][j] = zz;

    // A staging: 256 rows x 32 k = 1024 half8, 2/thread. B: 128 rows x 32 k, 1/thread.
    int arow = tid >> 2, ako = (tid & 3) * 8;   // rows 0..127 (+128 for second)
    const _Float16* ApA0 = A  + (size_t)(bm + arow) * K + ako;
    const _Float16* ApA1 = A  + (size_t)(bm + arow + 128) * K + ako;
    const _Float16* BpB  = Bt + (size_t)(bn + arow) * K + ako;

    half8 ra0 = *(const half8*)(ApA0);
    half8 ra1 = *(const half8*)(ApA1);
    half8 rb  = *(const half8*)(BpB);

    for (int k0 = 0; k0 < K; k0 += 32) {
        *(half8*)&As[arow * 40 + ako]         = ra0;
        *(half8*)&As[(arow + 128) * 40 + ako] = ra1;
        *(half8*)&Bs[arow * 40 + ako]         = rb;
        __syncthreads();
        if (k0 + 32 < K) {
            ra0 = *(const half8*)(ApA0 + k0 + 32);
            ra1 = *(const half8*)(ApA1 + k0 + 32);
            rb  = *(const half8*)(BpB  + k0 + 32);
        }
        half8 af[4], bf[4];
#pragma unroll
        for (int t = 0; t < 4; ++t) {
            af[t] = *(const half8*)&As[(mh + t * 16 + r) * 40 + quad * 8];
            bf[t] = *(const half8*)&Bs[(nh + t * 16 + r) * 40 + quad * 8];
        }
#pragma unroll
        for (int i = 0; i < 4; ++i)
#pragma unroll
            for (int j = 0; j < 4; ++j)
                acc[i][j] = __builtin_amdgcn_mfma_f32_16x16x32_f16(af[i], bf[j], acc[i][j], 0, 0, 0);
        __syncthreads();
    }

#pragma unroll
    for (int j = 0; j < 4; ++j) {
        int col = bn + nh + j * 16 + r;
        float bvv = bias[col];
#pragma unroll
        for (int i = 0; i < 4; ++i) {
#pragma unroll
            for (int g = 0; g < 4; ++g) {
                int row = bm + mh + i * 16 + quad * 4 + g;
                float v = acc[i][j][g] + bvv;
                if (!vt) {
                    out[(size_t)row * 512 + col] = (_Float16)v;
                } else {
                    int bb = row >> 12, pp = row & 4095;   // rows = b*4096 + p
                    int hh = col >> 6,  dd = col & 63;     // cols = h*64 + d
                    out[((size_t)((bb * 8 + hh) * 64 + dd)) * 4096 + pp] = (_Float16)v;
                }
            }
        }
    }
}

// ---------------- two-pass flash attention: stats pass + emit/PV pass, ONE kernel ----------------
// grid (S/32=16, B*H=16), 512 threads (8 waves). Block: 32 s-rows x all 4096 p.
// wave -> (sH = wave>>2: 16-row half, pQ = wave&3: 32-col quarter of the 128-p chunk).
// Pass 1: QK^T per 128-p chunk -> per-row online (m, l). Pass 2: recompute QK^T,
// write normalized attn f32 (nontemporal), PV-accumulate, write ctx f16 directly.
__global__ __launch_bounds__(512) void flash_attn_kernel(
    const _Float16* __restrict__ Qh, const _Float16* __restrict__ Kh,
    const _Float16* __restrict__ Vt,
    const float* __restrict__ edge_emb, const float* __restrict__ ep_w,
    const float* __restrict__ ep_b,
    float* __restrict__ attn, _Float16* __restrict__ ctx_h)
{
    __shared__ _Float16 Qs[32 * 72];     // 32 s x 64 k (+8 pad)
    __shared__ _Float16 Ks[128 * 72];    // 128 p x 64 k (+8 pad)
    __shared__ _Float16 Vs[64 * 136];    // 64 d x 128 p (+8 pad)
    __shared__ _Float16 As[32 * 136];    // 32 s x 128 p f16 probs (+8 pad)
    __shared__ float cm[8][32], cl[8][32];

    int s0 = blockIdx.x * 32;
    int bh = blockIdx.y, h = bh & 7, b = bh >> 3;
    int tid = threadIdx.x;
    int wave = tid >> 6, lane = tid & 63, quad = lane >> 4, r = lane & 15;
    int sH = wave >> 2, pQ = wave & 3;

    // stage Q once (32 rows x 64 halves = 256 half8)
    if (tid < 256) {
        int row = tid >> 3, ko = (tid & 7) * 8;
        *(half8*)&Qs[row * 72 + ko] =
            *(const half8*)(Qh + (size_t)(b * S_ + s0 + row) * TD_ + h * HD_ + ko);
    }
    float s_h = 0.f;
#pragma unroll
    for (int e = 0; e < 32; ++e) s_h += edge_emb[h * 32 + e] * ep_w[e];
    float epbv = ep_b[0];
    const float scale = 0.125f;

    const _Float16* Kbase = Kh + (size_t)b * P_ * TD_ + h * HD_;   // + p*TD_ + k
    const _Float16* Vbase = Vt + (size_t)bh * 64 * P_;             // + d*P_ + p

    // staging maps: K chunk 128x64 halves -> 2 half8/thread; V chunk 64x128 -> 2 half8/thread
    int krow = tid >> 3, kko = (tid & 7) * 8;       // K rows 0..63 (+64)
    int vrow = tid >> 4, vpo = (tid & 15) * 8;      // V rows 0..31 (+32)

    floatx4 zz = {0.f, 0.f, 0.f, 0.f};
    float m_run[4], l_run[4];
#pragma unroll
    for (int g = 0; g < 4; ++g) { m_run[g] = -1e30f; l_run[g] = 0.f; }

    // ---------------- pass 1: stats ----------------
    half8 rk0 = *(const half8*)(Kbase + (size_t)krow * TD_ + kko);
    half8 rk1 = *(const half8*)(Kbase + (size_t)(krow + 64) * TD_ + kko);

    for (int pc = 0; pc < P_; pc += 128) {
        *(half8*)&Ks[krow * 72 + kko]        = rk0;
        *(half8*)&Ks[(krow + 64) * 72 + kko] = rk1;
        __syncthreads();
        if (pc + 128 < P_) {
            rk0 = *(const half8*)(Kbase + (size_t)(pc + 128 + krow) * TD_ + kko);
            rk1 = *(const half8*)(Kbase + (size_t)(pc + 128 + krow + 64) * TD_ + kko);
        }
        floatx4 accs[2];
        accs[0] = zz; accs[1] = zz;
#pragma unroll
        for (int c2 = 0; c2 < 2; ++c2) {
            half8 aq = *(const half8*)&Qs[(sH * 16 + r) * 72 + c2 * 32 + quad * 8];
#pragma unroll
            for (int j = 0; j < 2; ++j) {
                half8 bk = *(const half8*)&Ks[(pQ * 32 + j * 16 + r) * 72 + c2 * 32 + quad * 8];
                accs[j] = __builtin_amdgcn_mfma_f32_16x16x32_f16(aq, bk, accs[j], 0, 0, 0);
            }
        }
        // transform + per-row chunk stats (rows sH*16 + quad*4 + g; cols pQ*32 + j*16 + r)
        float zv[2][4];
#pragma unroll
        for (int j = 0; j < 2; ++j)
#pragma unroll
            for (int g = 0; g < 4; ++g) {
                float base = accs[j][g] * scale;
                float t = fmaf(base, s_h, epbv);
                float e = (t >= 0.f) ? t : 0.2f * t;
                zv[j][g] = base + e;
            }
        float mw[4], sw[4];
#pragma unroll
        for (int g = 0; g < 4; ++g) {
            mw[g] = fmaxf(zv[0][g], zv[1][g]);
#pragma unroll
            for (int mask = 1; mask <= 8; mask <<= 1)
                mw[g] = fmaxf(mw[g], __shfl_xor(mw[g], mask));
            sw[g] = __expf(zv[0][g] - mw[g]) + __expf(zv[1][g] - mw[g]);
#pragma unroll
            for (int mask = 1; mask <= 8; mask <<= 1)
                sw[g] += __shfl_xor(sw[g], mask);
        }
        if (r == 0) {
#pragma unroll
            for (int g = 0; g < 4; ++g) {
                cm[wave][sH * 16 + quad * 4 + g] = mw[g];
                cl[wave][sH * 16 + quad * 4 + g] = sw[g];
            }
        }
        __syncthreads();
        // merge the 4 p-quarters (waves with same sH) into running stats
#pragma unroll
        for (int g = 0; g < 4; ++g) {
            int row = sH * 16 + quad * 4 + g;
#pragma unroll
            for (int q2 = 0; q2 < 4; ++q2) {
                float mc = cm[sH * 4 + q2][row];
                float lc = cl[sH * 4 + q2][row];
                float nm = fmaxf(m_run[g], mc);
                l_run[g] = l_run[g] * __expf(m_run[g] - nm) + lc * __expf(mc - nm);
                m_run[g] = nm;
            }
        }
    }
    float invl[4];
#pragma unroll
    for (int g = 0; g < 4; ++g) invl[g] = 1.0f / l_run[g];

    // ---------------- pass 2: emit attn + PV ----------------
    half8 prk0 = *(const half8*)(Kbase + (size_t)krow * TD_ + kko);
    half8 prk1 = *(const half8*)(Kbase + (size_t)(krow + 64) * TD_ + kko);
    half8 prv0 = *(const half8*)(Vbase + (size_t)vrow * P_ + vpo);
    half8 prv1 = *(const half8*)(Vbase + (size_t)(vrow + 32) * P_ + vpo);

    floatx4 accpv = zz;

    for (int pc = 0; pc < P_; pc += 128) {
        *(half8*)&Ks[krow * 72 + kko]         = prk0;
        *(half8*)&Ks[(krow + 64) * 72 + kko]  = prk1;
        *(half8*)&Vs[vrow * 136 + vpo]        = prv0;
        *(half8*)&Vs[(vrow + 32) * 136 + vpo] = prv1;
        __syncthreads();
        if (pc + 128 < P_) {
            prk0 = *(const half8*)(Kbase + (size_t)(pc + 128 + krow) * TD_ + kko);
            prk1 = *(const half8*)(Kbase + (size_t)(pc + 128 + krow + 64) * TD_ + kko);
            prv0 = *(const half8*)(Vbase + (size_t)vrow * P_ + pc + 128 + vpo);
            prv1 = *(const half8*)(Vbase + (size_t)(vrow + 32) * P_ + pc + 128 + vpo);
        }
        floatx4 accs[2];
        accs[0] = zz; accs[1] = zz;
#pragma unroll
        for (int c2 = 0; c2 < 2; ++c2) {
            half8 aq = *(const half8*)&Qs[(sH * 16 + r) * 72 + c2 * 32 + quad * 8];
#pragma unroll
            for (int j = 0; j < 2; ++j) {
                half8 bk = *(const half8*)&Ks[(pQ * 32 + j * 16 + r) * 72 + c2 * 32 + quad * 8];
                accs[j] = __builtin_amdgcn_mfma_f32_16x16x32_f16(aq, bk, accs[j], 0, 0, 0);
            }
        }
        // normalize + emit
#pragma unroll
        for (int j = 0; j < 2; ++j) {
            int colp = pQ * 32 + j * 16 + r;
#pragma unroll
            for (int g = 0; g < 4; ++g) {
                int srow = sH * 16 + quad * 4 + g;
                float base = accs[j][g] * scale;
                float t = fmaf(base, s_h, epbv);
                float e = (t >= 0.f) ? t : 0.2f * t;
                float z = base + e;
                float p = __expf(z - m_run[g]) * invl[g];
                __builtin_nontemporal_store(p, &attn[((size_t)bh * S_ + s0 + srow) * P_ + pc + colp]);
                As[srow * 136 + colp] = (_Float16)p;
            }
        }
        __syncthreads();   // As visible
        // PV: wave owns (sH 16-row half, d range pQ*16..+16)
#pragma unroll
        for (int cc = 0; cc < 4; ++cc) {
            half8 bv = *(const half8*)&Vs[(pQ * 16 + r) * 136 + cc * 32 + quad * 8];
            half8 ap = *(const half8*)&As[(sH * 16 + r) * 136 + cc * 32 + quad * 8];
            accpv = __builtin_amdgcn_mfma_f32_16x16x32_f16(ap, bv, accpv, 0, 0, 0);
        }
        __syncthreads();   // PV done reading Ks/Vs/As before next chunk's writes
    }

    // ctx f16 direct (rows s0+sH*16+quad*4+g, col d = pQ*16 + r)
#pragma unroll
    for (int g = 0; g < 4; ++g) {
        int srow = s0 + sH * 16 + quad * 4 + g;
        int d = pQ * 16 + r;
        ctx_h[(size_t)(b * S_ + srow) * TD_ + h * HD_ + d] = (_Float16)accpv[g];
    }
}

extern "C" void kernel_launch(void* const* d_in, const int* in_sizes, int n_in,
                              void* d_out, int out_size, void* d_ws, size_t ws_size,
                              hipStream_t stream) {
    const float* text  = (const float*)d_in[0];
    const float* shape = (const float*)d_in[1];
    const float* tn_g  = (const float*)d_in[2];
    const float* tn_b  = (const float*)d_in[3];
    const float* sn_g  = (const float*)d_in[4];
    const float* sn_b  = (const float*)d_in[5];
    const float* Wq    = (const float*)d_in[6];
    const float* bq    = (const float*)d_in[7];
    const float* Wk    = (const float*)d_in[8];
    const float* bk    = (const float*)d_in[9];
    const float* Wv    = (const float*)d_in[10];
    const float* bv    = (const float*)d_in[11];
    const float* edge  = (const float*)d_in[12];
    const float* epw   = (const float*)d_in[13];
    const float* epb   = (const float*)d_in[14];
    const float* Wo    = (const float*)d_in[15];
    const float* bo    = (const float*)d_in[16];
    const float* on_g  = (const float*)d_in[17];
    const float* on_b  = (const float*)d_in[18];
    const float* W1    = (const float*)d_in[19];
    const float* b1    = (const float*)d_in[20];
    const float* W2    = (const float*)d_in[21];
    const float* b2    = (const float*)d_in[22];
    const float* fn_g  = (const float*)d_in[23];
    const float* fn_b  = (const float*)d_in[24];

    float* out_f  = (float*)d_out;                       // [B,S,TD]
    float* attn_f = out_f + (size_t)B_ * S_ * TD_;       // [B,H,S,P]

    // workspace layout (bytes)
    char* w = (char*)d_ws;
    _Float16* tn_h   = (_Float16*)w; w += (size_t)1024 * 512 * 2;
    _Float16* sn_h   = (_Float16*)w; w += (size_t)8192 * 384 * 2;
    _Float16* Q_h    = (_Float16*)w; w += (size_t)1024 * 512 * 2;
    _Float16* K_h    = (_Float16*)w; w += (size_t)8192 * 512 * 2;
    _Float16* Vt_h   = (_Float16*)w; w += (size_t)16 * 64 * 4096 * 2;
    _Float16* ctx_h  = (_Float16*)w; w += (size_t)1024 * 512 * 2;
    _Float16* out1_h = (_Float16*)w; w += (size_t)1024 * 512 * 2;
    _Float16* h1_h   = (_Float16*)w; w += (size_t)1024 * 2048 * 2;
    _Float16* Wqt    = (_Float16*)w; w += (size_t)512 * 512 * 2;
    _Float16* Wkt    = (_Float16*)w; w += (size_t)512 * 384 * 2;
    _Float16* Wvt    = (_Float16*)w; w += (size_t)512 * 384 * 2;
    _Float16* Wot    = (_Float16*)w; w += (size_t)512 * 512 * 2;
    _Float16* W1t    = (_Float16*)w; w += (size_t)2048 * 512 * 2;
    _Float16* W2t    = (_Float16*)w; w += (size_t)512 * 2048 * 2;
    float*    out1_f = (float*)w;    w += (size_t)1024 * 512 * 4;
    float*    ctx_part = (float*)w;  w += (size_t)4 * 1024 * 512 * 4;  // 8.4 MB: Wo/FFN2 split-K partials

    // 0+1. weight transposes + both LayerNorms — one launch
    prep_kernel<<<2944 + 1024 + 8192, 256, 0, stream>>>(
        Wq, Wk, Wv, Wo, W1, W2, Wqt, Wkt, Wvt, Wot, W1t, W2t,
        text, shape, tn_g, tn_b, sn_g, sn_b, tn_h, sn_h);

    // 2. Q/K/V projections — one launch, 256x128 tiles (V written transposed into Vt)
    qkv_gemm_kernel<<<dim3(4, 68), 512, 0, stream>>>(tn_h, sn_h, Wqt, Wkt, Wvt,
                                                     bq, bk, bv, Q_h, K_h, Vt_h);

    // 3. attention — one two-pass flash kernel (stats + emit + PV + ctx f16)
    flash_attn_kernel<<<dim3(S_ / 32, B_ * H_), 512, 0, stream>>>(
        Q_h, K_h, Vt_h, edge, epw, epb, attn_f, ctx_h);

    // 4. output projection (split-K=4 -> partials) + residual LN (sums partials)
    gemm_f16_kernel<0,1,0,4><<<dim3(4, 8, 4), 256, 0, stream>>>(ctx_h, Wot, bo, ctx_part, nullptr, 1024, 512, 512);
    ln_add_kernel<<<B_ * S_, 256, 0, stream>>>(text, ctx_part, 4, 1024 * 512, on_g, on_b, out1_f, out1_h);

    // 5. FFN: FFN1 (gelu fused), FFN2 split-K=4 into ctx_part, summed in final LN
    gemm_f16_kernel<1,0,1,1><<<dim3(16, 8), 256, 0, stream>>>(out1_h, W1t, b1, nullptr, h1_h, 1024, 2048, 512);
    gemm_f16_kernel<0,1,0,4><<<dim3(4, 8, 4), 256, 0, stream>>>(h1_h, W2t, b2, ctx_part, nullptr, 1024, 512, 2048);
    ln_add_kernel<<<B_ * S_, 256, 0, stream>>>(out1_f, ctx_part, 4, 1024 * 512, fn_g, fn_b, out_f, nullptr);
}

// Round 6
// 357.176 us; speedup vs baseline: 1.0951x; 1.0951x over previous
//
#include <hip/hip_runtime.h>
#include <math.h>

// ---------- sizes (compile-time for this problem) ----------
#define B_  2
#define S_  512
#define P_  4096
#define TD_ 512
#define SD_ 384
#define H_  8
#define HD_ 64
#define FF_ 2048

typedef _Float16 half8 __attribute__((ext_vector_type(8)));
typedef _Float16 half4 __attribute__((ext_vector_type(4)));
typedef float floatx4 __attribute__((ext_vector_type(4)));

// ---------------- block reduction (sum of two values) ----------------
__device__ __forceinline__ float2 block_sum2(float a, float b) {
    for (int off = 32; off > 0; off >>= 1) {
        a += __shfl_down(a, off);
        b += __shfl_down(b, off);
    }
    __shared__ float sa[8], sb[8];
    int w = threadIdx.x >> 6;
    if ((threadIdx.x & 63) == 0) { sa[w] = a; sb[w] = b; }
    __syncthreads();
    int nw = blockDim.x >> 6;
    float ta = 0.f, tb = 0.f;
    for (int i = 0; i < nw; ++i) { ta += sa[i]; tb += sb[i]; }
    __syncthreads();
    return make_float2(ta, tb);
}

// ---------------- prep: 6 weight transposes + both input LayerNorms, ONE launch ----------------
__global__ __launch_bounds__(256) void prep_kernel(
    const float* __restrict__ s0p, const float* __restrict__ s1p,
    const float* __restrict__ s2p, const float* __restrict__ s3p,
    const float* __restrict__ s4p, const float* __restrict__ s5p,
    _Float16* __restrict__ d0p, _Float16* __restrict__ d1p,
    _Float16* __restrict__ d2p, _Float16* __restrict__ d3p,
    _Float16* __restrict__ d4p, _Float16* __restrict__ d5p,
    const float* __restrict__ text, const float* __restrict__ shape,
    const float* __restrict__ tn_g, const float* __restrict__ tn_b,
    const float* __restrict__ sn_g, const float* __restrict__ sn_b,
    _Float16* __restrict__ tn_h, _Float16* __restrict__ sn_h)
{
    __shared__ float ts[32][33];
    int id = blockIdx.x;
    int tid = threadIdx.x;
    if (id < 2944) {
        const float* src; _Float16* dst; int K, N, t, nlog;
        if (id < 256)       { src=s0p; dst=d0p; K=512;  N=512;  t=id;       nlog=4; }  // Wq
        else if (id < 448)  { src=s1p; dst=d1p; K=384;  N=512;  t=id-256;   nlog=4; }  // Wk
        else if (id < 640)  { src=s2p; dst=d2p; K=384;  N=512;  t=id-448;   nlog=4; }  // Wv
        else if (id < 896)  { src=s3p; dst=d3p; K=512;  N=512;  t=id-640;   nlog=4; }  // Wo
        else if (id < 1920) { src=s4p; dst=d4p; K=512;  N=2048; t=id-896;   nlog=6; }  // W1
        else                { src=s5p; dst=d5p; K=2048; N=512;  t=id-1920;  nlog=4; }  // W2
        int n0 = (t & ((1 << nlog) - 1)) << 5;
        int k0 = (t >> nlog) << 5;
#pragma unroll
        for (int i = 0; i < 4; ++i) {
            int e = i * 256 + tid;
            int kk = e >> 5, nn = e & 31;
            ts[kk][nn] = src[(size_t)(k0 + kk) * N + n0 + nn];
        }
        __syncthreads();
#pragma unroll
        for (int i = 0; i < 4; ++i) {
            int e = i * 256 + tid;
            int nn = e >> 5, kk = e & 31;
            dst[(size_t)(n0 + nn) * K + k0 + kk] = (_Float16)ts[kk][nn];
        }
        return;
    }
    int row = id - 2944;
    const float* xr; const float* g; const float* be; _Float16* yr; int D;
    if (row < 1024) {
        D = 512; xr = text + (size_t)row * 512; g = tn_g; be = tn_b;
        yr = tn_h + (size_t)row * 512;
    } else {
        int r2 = row - 1024;
        D = 384; xr = shape + (size_t)r2 * 384; g = sn_g; be = sn_b;
        yr = sn_h + (size_t)r2 * 384;
    }
    float s = 0.f, s2 = 0.f;
    for (int i = tid; i < D; i += 256) {
        float v = xr[i]; s += v; s2 += v * v;
    }
    float2 r = block_sum2(s, s2);
    float mean = r.x / (float)D;
    float var  = r.y / (float)D - mean * mean;
    float rstd = rsqrtf(var + 1e-5f);
    for (int i = tid; i < D; i += 256)
        yr[i] = (_Float16)((xr[i] - mean) * rstd * g[i] + be[i]);
}

// ---------------- LN (D=512): (f32 a + sum of np f32 partials) -> f32 and/or f16 out ----------------
__global__ __launch_bounds__(256) void ln_add_kernel(
    const float* __restrict__ a, const float* __restrict__ c, int np, int cstride,
    const float* __restrict__ g, const float* __restrict__ be,
    float* __restrict__ yf, _Float16* __restrict__ yh)
{
    int row = blockIdx.x;
    int i0 = threadIdx.x, i1 = threadIdx.x + 256;
    const float* ar = a + (size_t)row * 512;
    const float* cr = c + (size_t)row * 512;
    float v0 = ar[i0], v1 = ar[i1];
    for (int t = 0; t < np; ++t) {
        v0 += cr[(size_t)t * cstride + i0];
        v1 += cr[(size_t)t * cstride + i1];
    }
    float2 rd = block_sum2(v0 + v1, v0 * v0 + v1 * v1);
    float mean = rd.x / 512.f;
    float var  = rd.y / 512.f - mean * mean;
    float rstd = rsqrtf(var + 1e-5f);
    float o0 = (v0 - mean) * rstd * g[i0] + be[i0];
    float o1 = (v1 - mean) * rstd * g[i1] + be[i1];
    if (yf) { yf[(size_t)row * 512 + i0] = o0; yf[(size_t)row * 512 + i1] = o1; }
    if (yh) { yh[(size_t)row * 512 + i0] = (_Float16)o0; yh[(size_t)row * 512 + i1] = (_Float16)o1; }
}

// ---------------- MFMA GEMM: C[M,N] = A[M,K] @ Bt[N,K]^T + bias (tail GEMMs) ----------------
// 128x128 tile, BK=32, 4 waves each 64x64. T14 prefetch.
// ACT: 1=gelu. OUTF: write f32 C (at split offset). OUTH: write f16 C.
// SPLITK: blockIdx.z splits K; bias added only by split 0; f32 partials summed later.
template<int ACT, int OUTF, int OUTH, int SPLITK>
__global__ __launch_bounds__(256) void gemm_f16_kernel(
    const _Float16* __restrict__ A, const _Float16* __restrict__ Bt,
    const float* __restrict__ bias, float* __restrict__ Cf,
    _Float16* __restrict__ Ch, int M, int N, int K)
{
    __shared__ _Float16 As[128 * 40];
    __shared__ _Float16 Bs[128 * 40];
    int tid = threadIdx.x;
    int bm = blockIdx.y * 128, bn = blockIdx.x * 128;
    int wave = tid >> 6, lane = tid & 63, quad = lane >> 4, r = lane & 15;
    int mh = (wave & 1) * 64, nh = (wave >> 1) * 64;

    floatx4 acc[4][4];
    floatx4 zz = {0.f, 0.f, 0.f, 0.f};
#pragma unroll
    for (int i = 0; i < 4; ++i)
#pragma unroll
        for (int j = 0; j < 4; ++j) acc[i][j] = zz;

    int srow = tid >> 2;          // 0..63
    int sko  = (tid & 3) * 8;     // 0,8,16,24

    int ksplit = (SPLITK > 1) ? blockIdx.z : 0;
    int kbeg = ksplit * (K / SPLITK);
    int kend = kbeg + K / SPLITK;

    const _Float16* Ap0 = A  + (size_t)(bm + srow) * K + sko;
    const _Float16* Ap1 = A  + (size_t)(bm + srow + 64) * K + sko;
    const _Float16* Bp0 = Bt + (size_t)(bn + srow) * K + sko;
    const _Float16* Bp1 = Bt + (size_t)(bn + srow + 64) * K + sko;

    half8 ra0 = *(const half8*)(Ap0 + kbeg);
    half8 ra1 = *(const half8*)(Ap1 + kbeg);
    half8 rb0 = *(const half8*)(Bp0 + kbeg);
    half8 rb1 = *(const half8*)(Bp1 + kbeg);

    for (int k0 = kbeg; k0 < kend; k0 += 32) {
        *(half8*)&As[srow * 40 + sko]        = ra0;
        *(half8*)&As[(srow + 64) * 40 + sko] = ra1;
        *(half8*)&Bs[srow * 40 + sko]        = rb0;
        *(half8*)&Bs[(srow + 64) * 40 + sko] = rb1;
        __syncthreads();
        if (k0 + 32 < kend) {
            ra0 = *(const half8*)(Ap0 + k0 + 32);
            ra1 = *(const half8*)(Ap1 + k0 + 32);
            rb0 = *(const half8*)(Bp0 + k0 + 32);
            rb1 = *(const half8*)(Bp1 + k0 + 32);
        }
        half8 af[4], bf[4];
#pragma unroll
        for (int t = 0; t < 4; ++t) {
            af[t] = *(const half8*)&As[(mh + t * 16 + r) * 40 + quad * 8];
            bf[t] = *(const half8*)&Bs[(nh + t * 16 + r) * 40 + quad * 8];
        }
#pragma unroll
        for (int i = 0; i < 4; ++i)
#pragma unroll
            for (int j = 0; j < 4; ++j)
                acc[i][j] = __builtin_amdgcn_mfma_f32_16x16x32_f16(af[i], bf[j], acc[i][j], 0, 0, 0);
        __syncthreads();
    }

#pragma unroll
    for (int j = 0; j < 4; ++j) {
        int col = bn + nh + j * 16 + r;
        float bv = (SPLITK == 1 || ksplit == 0) ? bias[col] : 0.f;
#pragma unroll
        for (int i = 0; i < 4; ++i) {
#pragma unroll
            for (int g = 0; g < 4; ++g) {
                int row = bm + mh + i * 16 + quad * 4 + g;
                float v = acc[i][j][g] + bv;
                if (ACT) v = 0.5f * v * (1.0f + erff(v * 0.70710678118654752f));
                if (OUTF) Cf[(size_t)ksplit * M * N + (size_t)row * N + col] = v;
                if (OUTH) Ch[(size_t)row * N + col] = (_Float16)v;
            }
        }
    }
}

// ---------------- fused Q/K/V projection, 256x128 tiles, 512 threads ----------------
// grid (4, 68): y<4 -> Q (M=1024,K=512); y<36 -> K (M=8192,K=384); else V (scatter to Vt).
// 8 waves laid 4m x 2n, each 64x64 (4x4 MFMA). B-tile shared across 256 A-rows.
__global__ __launch_bounds__(512) void qkv_gemm_kernel(
    const _Float16* __restrict__ tn, const _Float16* __restrict__ sn,
    const _Float16* __restrict__ Wqt, const _Float16* __restrict__ Wkt,
    const _Float16* __restrict__ Wvt,
    const float* __restrict__ bq, const float* __restrict__ bk,
    const float* __restrict__ bv,
    _Float16* __restrict__ Qh, _Float16* __restrict__ Kh, _Float16* __restrict__ Vth)
{
    __shared__ _Float16 As[256 * 40];
    __shared__ _Float16 Bs[128 * 40];
    int by = blockIdx.y;
    const _Float16* A; const _Float16* Bt; const float* bias; _Float16* out;
    int K, bm, vt;
    if (by < 4)       { A = tn; Bt = Wqt; bias = bq; K = 512; bm = by * 256;        vt = 0; out = Qh;  }
    else if (by < 36) { A = sn; Bt = Wkt; bias = bk; K = 384; bm = (by - 4) * 256;  vt = 0; out = Kh;  }
    else              { A = sn; Bt = Wvt; bias = bv; K = 384; bm = (by - 36) * 256; vt = 1; out = Vth; }
    int bn = blockIdx.x * 128;
    int tid = threadIdx.x;
    int wave = tid >> 6, lane = tid & 63, quad = lane >> 4, r = lane & 15;
    int mh = (wave >> 1) * 64, nh = (wave & 1) * 64;

    floatx4 acc[4][4];
    floatx4 zz = {0.f, 0.f, 0.f, 0.f};
#pragma unroll
    for (int i = 0; i < 4; ++i)
#pragma unroll
        for (int j = 0; j < 4; ++j) acc[i][j] = zz;

    // A staging: 256 rows x 32 k = 1024 half8, 2/thread. B: 128 rows x 32 k, 1/thread.
    int arow = tid >> 2, ako = (tid & 3) * 8;   // rows 0..127 (+128 for second)
    const _Float16* ApA0 = A  + (size_t)(bm + arow) * K + ako;
    const _Float16* ApA1 = A  + (size_t)(bm + arow + 128) * K + ako;
    const _Float16* BpB  = Bt + (size_t)(bn + arow) * K + ako;

    half8 ra0 = *(const half8*)(ApA0);
    half8 ra1 = *(const half8*)(ApA1);
    half8 rb  = *(const half8*)(BpB);

    for (int k0 = 0; k0 < K; k0 += 32) {
        *(half8*)&As[arow * 40 + ako]         = ra0;
        *(half8*)&As[(arow + 128) * 40 + ako] = ra1;
        *(half8*)&Bs[arow * 40 + ako]         = rb;
        __syncthreads();
        if (k0 + 32 < K) {
            ra0 = *(const half8*)(ApA0 + k0 + 32);
            ra1 = *(const half8*)(ApA1 + k0 + 32);
            rb  = *(const half8*)(BpB  + k0 + 32);
        }
        half8 af[4], bf[4];
#pragma unroll
        for (int t = 0; t < 4; ++t) {
            af[t] = *(const half8*)&As[(mh + t * 16 + r) * 40 + quad * 8];
            bf[t] = *(const half8*)&Bs[(nh + t * 16 + r) * 40 + quad * 8];
        }
#pragma unroll
        for (int i = 0; i < 4; ++i)
#pragma unroll
            for (int j = 0; j < 4; ++j)
                acc[i][j] = __builtin_amdgcn_mfma_f32_16x16x32_f16(af[i], bf[j], acc[i][j], 0, 0, 0);
        __syncthreads();
    }

#pragma unroll
    for (int j = 0; j < 4; ++j) {
        int col = bn + nh + j * 16 + r;
        float bvv = bias[col];
#pragma unroll
        for (int i = 0; i < 4; ++i) {
#pragma unroll
            for (int g = 0; g < 4; ++g) {
                int row = bm + mh + i * 16 + quad * 4 + g;
                float v = acc[i][j][g] + bvv;
                if (!vt) {
                    out[(size_t)row * 512 + col] = (_Float16)v;
                } else {
                    int bb = row >> 12, pp = row & 4095;   // rows = b*4096 + p
                    int hh = col >> 6,  dd = col & 63;     // cols = h*64 + d
                    out[((size_t)((bb * 8 + hh) * 64 + dd)) * 4096 + pp] = (_Float16)v;
                }
            }
        }
    }
}

// ---------------- score stats: per-row (max, sum exp) partials per 128-col tile ----------------
// Output: part[ptile][bh*S + s] = (m_tile, l_tile) as float2, ptile = blockIdx.x (32 tiles).
__global__ __launch_bounds__(256) void score_stats_kernel(
    const _Float16* __restrict__ Qh, const _Float16* __restrict__ Kh,
    const float* __restrict__ edge_emb, const float* __restrict__ ep_w,
    const float* __restrict__ ep_b, float2* __restrict__ part)
{
    __shared__ _Float16 Qs[128 * 72];   // 64 k + 8 pad
    __shared__ _Float16 Ks[128 * 72];
    __shared__ float mred[2][128];
    __shared__ float sred[2][128];
    int p0 = blockIdx.x * 128, s0 = blockIdx.y * 128;
    int bh = blockIdx.z, h = bh & 7, b = bh >> 3;
    int tid = threadIdx.x;
    int wave = tid >> 6, lane = tid & 63, quad = lane >> 4, r = lane & 15;
    int mh = (wave & 1) * 64, nh = (wave >> 1) * 64;

#pragma unroll
    for (int i = 0; i < 4; ++i) {
        int row = i * 32 + (tid >> 3);
        int ko  = (tid & 7) * 8;
        *(half8*)&Qs[row * 72 + ko] = *(const half8*)(Qh + (size_t)(b * S_ + s0 + row) * TD_ + h * HD_ + ko);
        *(half8*)&Ks[row * 72 + ko] = *(const half8*)(Kh + (size_t)(b * P_ + p0 + row) * TD_ + h * HD_ + ko);
    }
    float s_h = 0.f;
#pragma unroll
    for (int e = 0; e < 32; ++e) s_h += edge_emb[h * 32 + e] * ep_w[e];
    float epbv = ep_b[0];
    __syncthreads();

    floatx4 acc[4][4];
    floatx4 zz = {0.f, 0.f, 0.f, 0.f};
#pragma unroll
    for (int i = 0; i < 4; ++i)
#pragma unroll
        for (int j = 0; j < 4; ++j) acc[i][j] = zz;

#pragma unroll
    for (int c = 0; c < 2; ++c) {
        half8 af[4], bf[4];
#pragma unroll
        for (int t = 0; t < 4; ++t) {
            af[t] = *(const half8*)&Qs[(mh + t * 16 + r) * 72 + c * 32 + quad * 8];
            bf[t] = *(const half8*)&Ks[(nh + t * 16 + r) * 72 + c * 32 + quad * 8];
        }
#pragma unroll
        for (int i = 0; i < 4; ++i)
#pragma unroll
            for (int j = 0; j < 4; ++j)
                acc[i][j] = __builtin_amdgcn_mfma_f32_16x16x32_f16(af[i], bf[j], acc[i][j], 0, 0, 0);
    }

    // transform scores in place: z = base + leaky_relu(base*s_h + epb)
    const float scale = 0.125f;
#pragma unroll
    for (int i = 0; i < 4; ++i)
#pragma unroll
        for (int j = 0; j < 4; ++j)
#pragma unroll
            for (int g = 0; g < 4; ++g) {
                float base = acc[i][j][g] * scale;
                float t = fmaf(base, s_h, epbv);
                float e = (t >= 0.f) ? t : 0.2f * t;
                acc[i][j][g] = base + e;
            }

    // per-row stats: rows indexed by (i, quad, g); cols by (j, r, nh)
    float mv[16], sv[16];
#pragma unroll
    for (int i = 0; i < 4; ++i)
#pragma unroll
        for (int g = 0; g < 4; ++g)
            mv[i * 4 + g] = fmaxf(fmaxf(acc[i][0][g], acc[i][1][g]),
                                  fmaxf(acc[i][2][g], acc[i][3][g]));
#pragma unroll
    for (int mask = 1; mask <= 8; mask <<= 1)
#pragma unroll
        for (int t = 0; t < 16; ++t)
            mv[t] = fmaxf(mv[t], __shfl_xor(mv[t], mask));
#pragma unroll
    for (int i = 0; i < 4; ++i)
#pragma unroll
        for (int g = 0; g < 4; ++g) {
            float s = 0.f;
#pragma unroll
            for (int j = 0; j < 4; ++j) s += __expf(acc[i][j][g] - mv[i * 4 + g]);
            sv[i * 4 + g] = s;
        }
#pragma unroll
    for (int mask = 1; mask <= 8; mask <<= 1)
#pragma unroll
        for (int t = 0; t < 16; ++t)
            sv[t] += __shfl_xor(sv[t], mask);

    if (r == 0) {
#pragma unroll
        for (int i = 0; i < 4; ++i)
#pragma unroll
            for (int g = 0; g < 4; ++g) {
                int row = mh + i * 16 + quad * 4 + g;
                mred[wave >> 1][row] = mv[i * 4 + g];
                sred[wave >> 1][row] = sv[i * 4 + g];
            }
    }
    __syncthreads();
    if (tid < 128) {
        float m0 = mred[0][tid], m1 = mred[1][tid];
        float m = fmaxf(m0, m1);
        float s = sred[0][tid] * __expf(m0 - m) + sred[1][tid] * __expf(m1 - m);
        part[(size_t)blockIdx.x * (B_ * H_ * S_) + (size_t)bh * S_ + s0 + tid] = make_float2(m, s);
    }
}

// ---------------- fused: rowstats -> recompute QK^T -> normalize -> attn f32 -> PV MFMA ----------------
// grid (S/32, 8 P-splits, B*H), 256 threads. Per block: 32 s-rows x 64 d, P-range 512 (4 chunks of 128).
// T14: K/V chunk staged global->regs early (during prev MFMA phase), regs->LDS late.
// attn written with nontemporal stores (never re-read). ctx split partials plain-stored.
__global__ __launch_bounds__(256) void attn_pv_kernel(
    const _Float16* __restrict__ Qh, const _Float16* __restrict__ Kh,
    const _Float16* __restrict__ Vt,
    const float* __restrict__ edge_emb, const float* __restrict__ ep_w,
    const float* __restrict__ ep_b, const float2* __restrict__ part,
    float* __restrict__ attn, float* __restrict__ ctx_part)
{
    __shared__ _Float16 Qs[32 * 72];     // 32 s x 64 k (+8 pad)
    __shared__ _Float16 Ks[128 * 72];    // 128 p x 64 k (+8 pad)
    __shared__ _Float16 Vs[64 * 136];    // 64 d x 128 p (+8 pad)
    __shared__ _Float16 As[32 * 136];    // 32 s x 128 p f16 probs (+8 pad)
    __shared__ float2 ms_sh[32];

    int s0 = blockIdx.x * 32;
    int split = blockIdx.y;              // 0..7, p-range 512
    int bh = blockIdx.z, h = bh & 7, b = bh >> 3;
    int tid = threadIdx.x;
    int wave = tid >> 6, lane = tid & 63, quad = lane >> 4, r = lane & 15;

    // stage Q once (32 rows x 64 halves = 256 half8, one per thread)
    {
        int row = tid >> 3, ko = (tid & 7) * 8;
        *(half8*)&Qs[row * 72 + ko] =
            *(const half8*)(Qh + (size_t)(b * S_ + s0 + row) * TD_ + h * HD_ + ko);
    }
    // fold rowstats: threads 0..31 each reduce the 32 per-tile partials of one row
    if (tid < 32) {
        int base = bh * S_ + s0 + tid;
        float2 v = part[base];
        float m = v.x, l = v.y;
#pragma unroll
        for (int t = 1; t < 32; ++t) {
            float2 p = part[(size_t)t * (B_ * H_ * S_) + base];
            float nm = fmaxf(m, p.x);
            l = l * __expf(m - nm) + p.y * __expf(p.x - nm);
            m = nm;
        }
        ms_sh[tid] = make_float2(m, 1.0f / l);
    }

    float s_h = 0.f;
#pragma unroll
    for (int e = 0; e < 32; ++e) s_h += edge_emb[h * 32 + e] * ep_w[e];
    float epbv = ep_b[0];

    const _Float16* Kbase = Kh + (size_t)b * P_ * TD_ + h * HD_;   // K[p] at + p*TD_
    const _Float16* Vbase = Vt + (size_t)bh * 64 * P_;             // Vt[d][p] at + d*P_ + p

    int pg0 = split * 512;
    half8 rk[4], rv[4];
    // prologue: prefetch chunk 0
#pragma unroll
    for (int ii = 0; ii < 4; ++ii) {
        int e = ii * 256 + tid;
        rk[ii] = *(const half8*)(Kbase + (size_t)(pg0 + (e >> 3)) * TD_ + (e & 7) * 8);
        rv[ii] = *(const half8*)(Vbase + (size_t)(e >> 4) * P_ + pg0 + (e & 15) * 8);
    }

    floatx4 zz = {0.f, 0.f, 0.f, 0.f};
    floatx4 accpv[2];
    accpv[0] = zz; accpv[1] = zz;
    const float scale = 0.125f;

    for (int c = 0; c < 4; ++c) {
        int pg = pg0 + c * 128;
        // write staged regs -> LDS (vmcnt wait here, ~1 chunk after issue)
#pragma unroll
        for (int ii = 0; ii < 4; ++ii) {
            int e = ii * 256 + tid;
            *(half8*)&Ks[(e >> 3) * 72 + (e & 7) * 8]  = rk[ii];
            *(half8*)&Vs[(e >> 4) * 136 + (e & 15) * 8] = rv[ii];
        }
        __syncthreads();
        // prefetch next chunk; latency hides under QK + epilogue + PV
        if (c < 3) {
            int pn = pg + 128;
#pragma unroll
            for (int ii = 0; ii < 4; ++ii) {
                int e = ii * 256 + tid;
                rk[ii] = *(const half8*)(Kbase + (size_t)(pn + (e >> 3)) * TD_ + (e & 7) * 8);
                rv[ii] = *(const half8*)(Vbase + (size_t)(e >> 4) * P_ + pn + (e & 15) * 8);
            }
        }

        // QK^T: per wave 32s x 32p (wave owns p sub-range wave*32)
        floatx4 accs[2][2];
        accs[0][0] = zz; accs[0][1] = zz; accs[1][0] = zz; accs[1][1] = zz;
#pragma unroll
        for (int c2 = 0; c2 < 2; ++c2) {
            half8 aq[2], bk2[2];
#pragma unroll
            for (int i = 0; i < 2; ++i)
                aq[i] = *(const half8*)&Qs[(i * 16 + r) * 72 + c2 * 32 + quad * 8];
#pragma unroll
            for (int j = 0; j < 2; ++j)
                bk2[j] = *(const half8*)&Ks[(wave * 32 + j * 16 + r) * 72 + c2 * 32 + quad * 8];
#pragma unroll
            for (int i = 0; i < 2; ++i)
#pragma unroll
                for (int j = 0; j < 2; ++j)
                    accs[i][j] = __builtin_amdgcn_mfma_f32_16x16x32_f16(aq[i], bk2[j], accs[i][j], 0, 0, 0);
        }

        // epilogue: z -> p = exp(z - m) * invl; nontemporal attn write; f16 into As
#pragma unroll
        for (int i = 0; i < 2; ++i)
#pragma unroll
            for (int j = 0; j < 2; ++j) {
                int colp = wave * 32 + j * 16 + r;
#pragma unroll
                for (int g = 0; g < 4; ++g) {
                    int srow = i * 16 + quad * 4 + g;
                    float base = accs[i][j][g] * scale;
                    float t = fmaf(base, s_h, epbv);
                    float e = (t >= 0.f) ? t : 0.2f * t;
                    float z = base + e;
                    float2 ms = ms_sh[srow];
                    float p = __expf(z - ms.x) * ms.y;
                    __builtin_nontemporal_store(p, &attn[((size_t)bh * S_ + s0 + srow) * P_ + pg + colp]);
                    As[srow * 136 + colp] = (_Float16)p;
                }
            }
        __syncthreads();   // As visible

        // PV: wave owns d in [wave*16, wave*16+16); K = 128 p in 4 chunks of 32
#pragma unroll
        for (int cc = 0; cc < 4; ++cc) {
            half8 bv = *(const half8*)&Vs[(wave * 16 + r) * 136 + cc * 32 + quad * 8];
#pragma unroll
            for (int i2 = 0; i2 < 2; ++i2) {
                half8 ap = *(const half8*)&As[(i2 * 16 + r) * 136 + cc * 32 + quad * 8];
                accpv[i2] = __builtin_amdgcn_mfma_f32_16x16x32_f16(ap, bv, accpv[i2], 0, 0, 0);
            }
        }
        __syncthreads();   // PV done reading Ks/Vs/As before next chunk's ds_write
    }

    // write split partial (plain store; every element covered exactly once per split)
    float* dst = ctx_part + (size_t)split * (1024 * 512);
#pragma unroll
    for (int i2 = 0; i2 < 2; ++i2)
#pragma unroll
        for (int g = 0; g < 4; ++g) {
            int srow = s0 + i2 * 16 + quad * 4 + g;
            int d = wave * 16 + r;
            dst[(size_t)(b * S_ + srow) * TD_ + h * HD_ + d] = accpv[i2][g];
        }
}

// ---------------- sum 8 split partials f32 -> ctx f16 ----------------
__global__ __launch_bounds__(256) void sumcast_kernel(
    const float4* __restrict__ src, _Float16* __restrict__ dst, int n4)
{
    int i = blockIdx.x * 256 + threadIdx.x;
    if (i < n4) {
        float4 v = src[i];
#pragma unroll
        for (int t = 1; t < 8; ++t) {
            float4 p = src[i + t * 131072];
            v.x += p.x; v.y += p.y; v.z += p.z; v.w += p.w;
        }
        half4 hv = { (_Float16)v.x, (_Float16)v.y, (_Float16)v.z, (_Float16)v.w };
        *(half4*)&dst[(size_t)i * 4] = hv;
    }
}

extern "C" void kernel_launch(void* const* d_in, const int* in_sizes, int n_in,
                              void* d_out, int out_size, void* d_ws, size_t ws_size,
                              hipStream_t stream) {
    const float* text  = (const float*)d_in[0];
    const float* shape = (const float*)d_in[1];
    const float* tn_g  = (const float*)d_in[2];
    const float* tn_b  = (const float*)d_in[3];
    const float* sn_g  = (const float*)d_in[4];
    const float* sn_b  = (const float*)d_in[5];
    const float* Wq    = (const float*)d_in[6];
    const float* bq    = (const float*)d_in[7];
    const float* Wk    = (const float*)d_in[8];
    const float* bk    = (const float*)d_in[9];
    const float* Wv    = (const float*)d_in[10];
    const float* bv    = (const float*)d_in[11];
    const float* edge  = (const float*)d_in[12];
    const float* epw   = (const float*)d_in[13];
    const float* epb   = (const float*)d_in[14];
    const float* Wo    = (const float*)d_in[15];
    const float* bo    = (const float*)d_in[16];
    const float* on_g  = (const float*)d_in[17];
    const float* on_b  = (const float*)d_in[18];
    const float* W1    = (const float*)d_in[19];
    const float* b1    = (const float*)d_in[20];
    const float* W2    = (const float*)d_in[21];
    const float* b2    = (const float*)d_in[22];
    const float* fn_g  = (const float*)d_in[23];
    const float* fn_b  = (const float*)d_in[24];

    float* out_f  = (float*)d_out;                       // [B,S,TD]
    float* attn_f = out_f + (size_t)B_ * S_ * TD_;       // [B,H,S,P]

    // workspace layout (bytes) — ~58.5 MB
    char* w = (char*)d_ws;
    _Float16* tn_h   = (_Float16*)w; w += (size_t)1024 * 512 * 2;
    _Float16* sn_h   = (_Float16*)w; w += (size_t)8192 * 384 * 2;
    _Float16* Q_h    = (_Float16*)w; w += (size_t)1024 * 512 * 2;
    _Float16* K_h    = (_Float16*)w; w += (size_t)8192 * 512 * 2;
    _Float16* Vt_h   = (_Float16*)w; w += (size_t)16 * 64 * 4096 * 2;
    _Float16* ctx_h  = (_Float16*)w; w += (size_t)1024 * 512 * 2;
    _Float16* out1_h = (_Float16*)w; w += (size_t)1024 * 512 * 2;
    _Float16* h1_h   = (_Float16*)w; w += (size_t)1024 * 2048 * 2;
    _Float16* Wqt    = (_Float16*)w; w += (size_t)512 * 512 * 2;
    _Float16* Wkt    = (_Float16*)w; w += (size_t)512 * 384 * 2;
    _Float16* Wvt    = (_Float16*)w; w += (size_t)512 * 384 * 2;
    _Float16* Wot    = (_Float16*)w; w += (size_t)512 * 512 * 2;
    _Float16* W1t    = (_Float16*)w; w += (size_t)2048 * 512 * 2;
    _Float16* W2t    = (_Float16*)w; w += (size_t)512 * 2048 * 2;
    float*    out1_f = (float*)w;    w += (size_t)1024 * 512 * 4;
    float*    ctx_part = (float*)w;  w += (size_t)8 * 1024 * 512 * 4;  // 16.8 MB: attn ctx splits; reused for Wo/FFN2 splits

    // part (2 MB) aliases sn_h (6.29 MB; dead after QKV projections)
    float2* part = (float2*)sn_h;                       // [32][8192]

    // 0+1. weight transposes + both LayerNorms — one launch
    prep_kernel<<<2944 + 1024 + 8192, 256, 0, stream>>>(
        Wq, Wk, Wv, Wo, W1, W2, Wqt, Wkt, Wvt, Wot, W1t, W2t,
        text, shape, tn_g, tn_b, sn_g, sn_b, tn_h, sn_h);

    // 2. Q/K/V projections — one launch, 256x128 tiles (V written transposed into Vt)
    qkv_gemm_kernel<<<dim3(4, 68), 512, 0, stream>>>(tn_h, sn_h, Wqt, Wkt, Wvt,
                                                     bq, bk, bv, Q_h, K_h, Vt_h);

    // 3. attention: stats (2048 blocks) -> fused pv (2048 blocks) -> sumcast
    score_stats_kernel<<<dim3(P_ / 128, S_ / 128, B_ * H_), 256, 0, stream>>>(
        Q_h, K_h, edge, epw, epb, part);
    attn_pv_kernel<<<dim3(S_ / 32, 8, B_ * H_), 256, 0, stream>>>(
        Q_h, K_h, Vt_h, edge, epw, epb, part, attn_f, ctx_part);
    sumcast_kernel<<<dim3(512), 256, 0, stream>>>((const float4*)ctx_part, ctx_h, 131072);

    // 4. output projection (split-K=4 -> partials) + residual LN (sums partials)
    gemm_f16_kernel<0,1,0,4><<<dim3(4, 8, 4), 256, 0, stream>>>(ctx_h, Wot, bo, ctx_part, nullptr, 1024, 512, 512);
    ln_add_kernel<<<B_ * S_, 256, 0, stream>>>(text, ctx_part, 4, 1024 * 512, on_g, on_b, out1_f, out1_h);

    // 5. FFN: FFN1 (gelu fused), FFN2 split-K=4 into ctx_part, summed in final LN
    gemm_f16_kernel<1,0,1,1><<<dim3(16, 8), 256, 0, stream>>>(out1_h, W1t, b1, nullptr, h1_h, 1024, 2048, 512);
    gemm_f16_kernel<0,1,0,4><<<dim3(4, 8, 4), 256, 0, stream>>>(h1_h, W2t, b2, ctx_part, nullptr, 1024, 512, 2048);
    ln_add_kernel<<<B_ * S_, 256, 0, stream>>>(out1_f, ctx_part, 4, 1024 * 512, fn_g, fn_b, out_f, nullptr);
}

// Round 8
// 334.881 us; speedup vs baseline: 1.1680x; 1.0666x over previous
//
#include <hip/hip_runtime.h>
#include <math.h>

// ---------- sizes (compile-time for this problem) ----------
#define B_  2
#define S_  512
#define P_  4096
#define TD_ 512
#define SD_ 384
#define H_  8
#define HD_ 64
#define FF_ 2048

typedef _Float16 half8 __attribute__((ext_vector_type(8)));
typedef _Float16 half4 __attribute__((ext_vector_type(4)));
typedef float floatx4 __attribute__((ext_vector_type(4)));

__device__ __forceinline__ half8 f4x2_to_h8(float4 a, float4 b) {
    half8 r;
    r[0] = (_Float16)a.x; r[1] = (_Float16)a.y; r[2] = (_Float16)a.z; r[3] = (_Float16)a.w;
    r[4] = (_Float16)b.x; r[5] = (_Float16)b.y; r[6] = (_Float16)b.z; r[7] = (_Float16)b.w;
    return r;
}

// ---------------- block reduction (sum of two values) ----------------
__device__ __forceinline__ float2 block_sum2(float a, float b) {
    for (int off = 32; off > 0; off >>= 1) {
        a += __shfl_down(a, off);
        b += __shfl_down(b, off);
    }
    __shared__ float sa[8], sb[8];
    int w = threadIdx.x >> 6;
    if ((threadIdx.x & 63) == 0) { sa[w] = a; sb[w] = b; }
    __syncthreads();
    int nw = blockDim.x >> 6;
    float ta = 0.f, tb = 0.f;
    for (int i = 0; i < nw; ++i) { ta += sa[i]; tb += sb[i]; }
    __syncthreads();
    return make_float2(ta, tb);
}

// ---------------- prep: 6 weight transposes + both input LayerNorms + ctx zero, ONE launch ----------------
// blocks 0..2943: transpose tiles. 2944..12159: LN rows. 12160..12671: zero ctx_f32 (2 MB).
__global__ __launch_bounds__(256) void prep_kernel(
    const float* __restrict__ s0p, const float* __restrict__ s1p,
    const float* __restrict__ s2p, const float* __restrict__ s3p,
    const float* __restrict__ s4p, const float* __restrict__ s5p,
    _Float16* __restrict__ d0p, _Float16* __restrict__ d1p,
    _Float16* __restrict__ d2p, _Float16* __restrict__ d3p,
    _Float16* __restrict__ d4p, _Float16* __restrict__ d5p,
    const float* __restrict__ text, const float* __restrict__ shape,
    const float* __restrict__ tn_g, const float* __restrict__ tn_b,
    const float* __restrict__ sn_g, const float* __restrict__ sn_b,
    _Float16* __restrict__ tn_h, _Float16* __restrict__ sn_h,
    float* __restrict__ ctx_zero)
{
    __shared__ float ts[32][33];
    int id = blockIdx.x;
    int tid = threadIdx.x;
    if (id < 2944) {
        const float* src; _Float16* dst; int K, N, t, nlog;
        if (id < 256)       { src=s0p; dst=d0p; K=512;  N=512;  t=id;       nlog=4; }  // Wq
        else if (id < 448)  { src=s1p; dst=d1p; K=384;  N=512;  t=id-256;   nlog=4; }  // Wk
        else if (id < 640)  { src=s2p; dst=d2p; K=384;  N=512;  t=id-448;   nlog=4; }  // Wv
        else if (id < 896)  { src=s3p; dst=d3p; K=512;  N=512;  t=id-640;   nlog=4; }  // Wo
        else if (id < 1920) { src=s4p; dst=d4p; K=512;  N=2048; t=id-896;   nlog=6; }  // W1
        else                { src=s5p; dst=d5p; K=2048; N=512;  t=id-1920;  nlog=4; }  // W2
        int n0 = (t & ((1 << nlog) - 1)) << 5;
        int k0 = (t >> nlog) << 5;
#pragma unroll
        for (int i = 0; i < 4; ++i) {
            int e = i * 256 + tid;
            int kk = e >> 5, nn = e & 31;
            ts[kk][nn] = src[(size_t)(k0 + kk) * N + n0 + nn];
        }
        __syncthreads();
#pragma unroll
        for (int i = 0; i < 4; ++i) {
            int e = i * 256 + tid;
            int nn = e >> 5, kk = e & 31;
            dst[(size_t)(n0 + nn) * K + k0 + kk] = (_Float16)ts[kk][nn];
        }
        return;
    }
    if (id >= 12160) {   // zero ctx accumulator (512 blocks x 256 x float4 = 2 MB)
        int i = (id - 12160) * 256 + tid;
        ((float4*)ctx_zero)[i] = make_float4(0.f, 0.f, 0.f, 0.f);
        return;
    }
    int row = id - 2944;
    const float* xr; const float* g; const float* be; _Float16* yr; int D;
    if (row < 1024) {
        D = 512; xr = text + (size_t)row * 512; g = tn_g; be = tn_b;
        yr = tn_h + (size_t)row * 512;
    } else {
        int r2 = row - 1024;
        D = 384; xr = shape + (size_t)r2 * 384; g = sn_g; be = sn_b;
        yr = sn_h + (size_t)r2 * 384;
    }
    float s = 0.f, s2 = 0.f;
    for (int i = tid; i < D; i += 256) {
        float v = xr[i]; s += v; s2 += v * v;
    }
    float2 r = block_sum2(s, s2);
    float mean = r.x / (float)D;
    float var  = r.y / (float)D - mean * mean;
    float rstd = rsqrtf(var + 1e-5f);
    for (int i = tid; i < D; i += 256)
        yr[i] = (_Float16)((xr[i] - mean) * rstd * g[i] + be[i]);
}

// ---------------- LN (D=512): (f32 a + sum of np f32 partials) -> f32 and/or f16 out ----------------
__global__ __launch_bounds__(256) void ln_add_kernel(
    const float* __restrict__ a, const float* __restrict__ c, int np, int cstride,
    const float* __restrict__ g, const float* __restrict__ be,
    float* __restrict__ yf, _Float16* __restrict__ yh)
{
    int row = blockIdx.x;
    int i0 = threadIdx.x, i1 = threadIdx.x + 256;
    const float* ar = a + (size_t)row * 512;
    const float* cr = c + (size_t)row * 512;
    float v0 = ar[i0], v1 = ar[i1];
    for (int t = 0; t < np; ++t) {
        v0 += cr[(size_t)t * cstride + i0];
        v1 += cr[(size_t)t * cstride + i1];
    }
    float2 rd = block_sum2(v0 + v1, v0 * v0 + v1 * v1);
    float mean = rd.x / 512.f;
    float var  = rd.y / 512.f - mean * mean;
    float rstd = rsqrtf(var + 1e-5f);
    float o0 = (v0 - mean) * rstd * g[i0] + be[i0];
    float o1 = (v1 - mean) * rstd * g[i1] + be[i1];
    if (yf) { yf[(size_t)row * 512 + i0] = o0; yf[(size_t)row * 512 + i1] = o1; }
    if (yh) { yh[(size_t)row * 512 + i0] = (_Float16)o0; yh[(size_t)row * 512 + i1] = (_Float16)o1; }
}

// ---------------- MFMA GEMM: C[M,N] = A[M,K] @ Bt[N,K]^T + bias (tail GEMMs) ----------------
// 128x128 tile, BK=32, 4 waves each 64x64. T14 prefetch.
// ACT: 1=gelu. OUTF: write f32 C (at split offset). OUTH: write f16 C.
// SPLITK: blockIdx.z splits K. AF32: A operand is f32 (converted during staging).
template<int ACT, int OUTF, int OUTH, int SPLITK, int AF32>
__global__ __launch_bounds__(256) void gemm_f16_kernel(
    const _Float16* __restrict__ A, const _Float16* __restrict__ Bt,
    const float* __restrict__ bias, float* __restrict__ Cf,
    _Float16* __restrict__ Ch, int M, int N, int K)
{
    __shared__ _Float16 As[128 * 40];
    __shared__ _Float16 Bs[128 * 40];
    int tid = threadIdx.x;
    int bm = blockIdx.y * 128, bn = blockIdx.x * 128;
    int wave = tid >> 6, lane = tid & 63, quad = lane >> 4, r = lane & 15;
    int mh = (wave & 1) * 64, nh = (wave >> 1) * 64;

    floatx4 acc[4][4];
    floatx4 zz = {0.f, 0.f, 0.f, 0.f};
#pragma unroll
    for (int i = 0; i < 4; ++i)
#pragma unroll
        for (int j = 0; j < 4; ++j) acc[i][j] = zz;

    int srow = tid >> 2;          // 0..63
    int sko  = (tid & 3) * 8;     // 0,8,16,24

    int ksplit = (SPLITK > 1) ? blockIdx.z : 0;
    int kbeg = ksplit * (K / SPLITK);
    int kend = kbeg + K / SPLITK;

    const float*    Af  = (const float*)A;
    const _Float16* Ap0 = A  + (size_t)(bm + srow) * K + sko;
    const _Float16* Ap1 = A  + (size_t)(bm + srow + 64) * K + sko;
    const float*    Af0 = Af + (size_t)(bm + srow) * K + sko;
    const float*    Af1 = Af + (size_t)(bm + srow + 64) * K + sko;
    const _Float16* Bp0 = Bt + (size_t)(bn + srow) * K + sko;
    const _Float16* Bp1 = Bt + (size_t)(bn + srow + 64) * K + sko;

    half8 ra0, ra1;
    float4 fa0l, fa0h, fa1l, fa1h;
    if (AF32) {
        fa0l = *(const float4*)(Af0 + kbeg); fa0h = *(const float4*)(Af0 + kbeg + 4);
        fa1l = *(const float4*)(Af1 + kbeg); fa1h = *(const float4*)(Af1 + kbeg + 4);
    } else {
        ra0 = *(const half8*)(Ap0 + kbeg);
        ra1 = *(const half8*)(Ap1 + kbeg);
    }
    half8 rb0 = *(const half8*)(Bp0 + kbeg);
    half8 rb1 = *(const half8*)(Bp1 + kbeg);

    for (int k0 = kbeg; k0 < kend; k0 += 32) {
        if (AF32) {
            *(half8*)&As[srow * 40 + sko]        = f4x2_to_h8(fa0l, fa0h);
            *(half8*)&As[(srow + 64) * 40 + sko] = f4x2_to_h8(fa1l, fa1h);
        } else {
            *(half8*)&As[srow * 40 + sko]        = ra0;
            *(half8*)&As[(srow + 64) * 40 + sko] = ra1;
        }
        *(half8*)&Bs[srow * 40 + sko]        = rb0;
        *(half8*)&Bs[(srow + 64) * 40 + sko] = rb1;
        __syncthreads();
        if (k0 + 32 < kend) {
            if (AF32) {
                fa0l = *(const float4*)(Af0 + k0 + 32); fa0h = *(const float4*)(Af0 + k0 + 36);
                fa1l = *(const float4*)(Af1 + k0 + 32); fa1h = *(const float4*)(Af1 + k0 + 36);
            } else {
                ra0 = *(const half8*)(Ap0 + k0 + 32);
                ra1 = *(const half8*)(Ap1 + k0 + 32);
            }
            rb0 = *(const half8*)(Bp0 + k0 + 32);
            rb1 = *(const half8*)(Bp1 + k0 + 32);
        }
        half8 af[4], bf[4];
#pragma unroll
        for (int t = 0; t < 4; ++t) {
            af[t] = *(const half8*)&As[(mh + t * 16 + r) * 40 + quad * 8];
            bf[t] = *(const half8*)&Bs[(nh + t * 16 + r) * 40 + quad * 8];
        }
#pragma unroll
        for (int i = 0; i < 4; ++i)
#pragma unroll
            for (int j = 0; j < 4; ++j)
                acc[i][j] = __builtin_amdgcn_mfma_f32_16x16x32_f16(af[i], bf[j], acc[i][j], 0, 0, 0);
        __syncthreads();
    }

#pragma unroll
    for (int j = 0; j < 4; ++j) {
        int col = bn + nh + j * 16 + r;
        float bv = (SPLITK == 1 || ksplit == 0) ? bias[col] : 0.f;
#pragma unroll
        for (int i = 0; i < 4; ++i) {
#pragma unroll
            for (int g = 0; g < 4; ++g) {
                int row = bm + mh + i * 16 + quad * 4 + g;
                float v = acc[i][j][g] + bv;
                if (ACT) v = 0.5f * v * (1.0f + erff(v * 0.70710678118654752f));
                if (OUTF) Cf[(size_t)ksplit * M * N + (size_t)row * N + col] = v;
                if (OUTH) Ch[(size_t)row * N + col] = (_Float16)v;
            }
        }
    }
}

// ---------------- fused Q/K/V projection, 256x128 tiles, 512 threads ----------------
__global__ __launch_bounds__(512) void qkv_gemm_kernel(
    const _Float16* __restrict__ tn, const _Float16* __restrict__ sn,
    const _Float16* __restrict__ Wqt, const _Float16* __restrict__ Wkt,
    const _Float16* __restrict__ Wvt,
    const float* __restrict__ bq, const float* __restrict__ bk,
    const float* __restrict__ bv,
    _Float16* __restrict__ Qh, _Float16* __restrict__ Kh, _Float16* __restrict__ Vth)
{
    __shared__ _Float16 As[256 * 40];
    __shared__ _Float16 Bs[128 * 40];
    int by = blockIdx.y;
    const _Float16* A; const _Float16* Bt; const float* bias; _Float16* out;
    int K, bm, vt;
    if (by < 4)       { A = tn; Bt = Wqt; bias = bq; K = 512; bm = by * 256;        vt = 0; out = Qh;  }
    else if (by < 36) { A = sn; Bt = Wkt; bias = bk; K = 384; bm = (by - 4) * 256;  vt = 0; out = Kh;  }
    else              { A = sn; Bt = Wvt; bias = bv; K = 384; bm = (by - 36) * 256; vt = 1; out = Vth; }
    int bn = blockIdx.x * 128;
    int tid = threadIdx.x;
    int wave = tid >> 6, lane = tid & 63, quad = lane >> 4, r = lane & 15;
    int mh = (wave >> 1) * 64, nh = (wave & 1) * 64;

    floatx4 acc[4][4];
    floatx4 zz = {0.f, 0.f, 0.f, 0.f};
#pragma unroll
    for (int i = 0; i < 4; ++i)
#pragma unroll
        for (int j = 0; j < 4; ++j) acc[i][j] = zz;

    int arow = tid >> 2, ako = (tid & 3) * 8;
    const _Float16* ApA0 = A  + (size_t)(bm + arow) * K + ako;
    const _Float16* ApA1 = A  + (size_t)(bm + arow + 128) * K + ako;
    const _Float16* BpB  = Bt + (size_t)(bn + arow) * K + ako;

    half8 ra0 = *(const half8*)(ApA0);
    half8 ra1 = *(const half8*)(ApA1);
    half8 rb  = *(const half8*)(BpB);

    for (int k0 = 0; k0 < K; k0 += 32) {
        *(half8*)&As[arow * 40 + ako]         = ra0;
        *(half8*)&As[(arow + 128) * 40 + ako] = ra1;
        *(half8*)&Bs[arow * 40 + ako]         = rb;
        __syncthreads();
        if (k0 + 32 < K) {
            ra0 = *(const half8*)(ApA0 + k0 + 32);
            ra1 = *(const half8*)(ApA1 + k0 + 32);
            rb  = *(const half8*)(BpB  + k0 + 32);
        }
        half8 af[4], bf[4];
#pragma unroll
        for (int t = 0; t < 4; ++t) {
            af[t] = *(const half8*)&As[(mh + t * 16 + r) * 40 + quad * 8];
            bf[t] = *(const half8*)&Bs[(nh + t * 16 + r) * 40 + quad * 8];
        }
#pragma unroll
        for (int i = 0; i < 4; ++i)
#pragma unroll
            for (int j = 0; j < 4; ++j)
                acc[i][j] = __builtin_amdgcn_mfma_f32_16x16x32_f16(af[i], bf[j], acc[i][j], 0, 0, 0);
        __syncthreads();
    }

#pragma unroll
    for (int j = 0; j < 4; ++j) {
        int col = bn + nh + j * 16 + r;
        float bvv = bias[col];
#pragma unroll
        for (int i = 0; i < 4; ++i) {
#pragma unroll
            for (int g = 0; g < 4; ++g) {
                int row = bm + mh + i * 16 + quad * 4 + g;
                float v = acc[i][j][g] + bvv;
                if (!vt) {
                    out[(size_t)row * 512 + col] = (_Float16)v;
                } else {
                    int bb = row >> 12, pp = row & 4095;   // rows = b*4096 + p
                    int hh = col >> 6,  dd = col & 63;     // cols = h*64 + d
                    out[((size_t)((bb * 8 + hh) * 64 + dd)) * 4096 + pp] = (_Float16)v;
                }
            }
        }
    }
}

// ---------------- score stats: per-row (max, sum exp) partials per 128-col tile ----------------
// 1D grid 2048, XCD-swizzled: the 4 s0-blocks sharing a (p0,bh) K-tile land on one XCD.
__global__ __launch_bounds__(256) void score_stats_kernel(
    const _Float16* __restrict__ Qh, const _Float16* __restrict__ Kh,
    const float* __restrict__ edge_emb, const float* __restrict__ ep_w,
    const float* __restrict__ ep_b, float2* __restrict__ part)
{
    __shared__ _Float16 Qs[128 * 72];   // 64 k + 8 pad
    __shared__ _Float16 Ks[128 * 72];
    __shared__ float mred[2][128];
    __shared__ float sred[2][128];
    // swizzle: bid = slot + 8*idx; group g = slot + 8*(idx>>2) -> (p0,bh); s0i = idx&3.
    int bid = blockIdx.x;
    int slot = bid & 7, idx = bid >> 3;
    int g4 = slot + 8 * (idx >> 2);     // 0..511
    int s0 = (idx & 3) * 128;
    int p0 = (g4 & 31) * 128;
    int bh = g4 >> 5, h = bh & 7, b = bh >> 3;
    int tid = threadIdx.x;
    int wave = tid >> 6, lane = tid & 63, quad = lane >> 4, r = lane & 15;
    int mh = (wave & 1) * 64, nh = (wave >> 1) * 64;

#pragma unroll
    for (int i = 0; i < 4; ++i) {
        int row = i * 32 + (tid >> 3);
        int ko  = (tid & 7) * 8;
        *(half8*)&Qs[row * 72 + ko] = *(const half8*)(Qh + (size_t)(b * S_ + s0 + row) * TD_ + h * HD_ + ko);
        *(half8*)&Ks[row * 72 + ko] = *(const half8*)(Kh + (size_t)(b * P_ + p0 + row) * TD_ + h * HD_ + ko);
    }
    float s_h = 0.f;
#pragma unroll
    for (int e = 0; e < 32; ++e) s_h += edge_emb[h * 32 + e] * ep_w[e];
    float epbv = ep_b[0];
    __syncthreads();

    floatx4 acc[4][4];
    floatx4 zz = {0.f, 0.f, 0.f, 0.f};
#pragma unroll
    for (int i = 0; i < 4; ++i)
#pragma unroll
        for (int j = 0; j < 4; ++j) acc[i][j] = zz;

#pragma unroll
    for (int c = 0; c < 2; ++c) {
        half8 af[4], bf[4];
#pragma unroll
        for (int t = 0; t < 4; ++t) {
            af[t] = *(const half8*)&Qs[(mh + t * 16 + r) * 72 + c * 32 + quad * 8];
            bf[t] = *(const half8*)&Ks[(nh + t * 16 + r) * 72 + c * 32 + quad * 8];
        }
#pragma unroll
        for (int i = 0; i < 4; ++i)
#pragma unroll
            for (int j = 0; j < 4; ++j)
                acc[i][j] = __builtin_amdgcn_mfma_f32_16x16x32_f16(af[i], bf[j], acc[i][j], 0, 0, 0);
    }

    const float scale = 0.125f;
#pragma unroll
    for (int i = 0; i < 4; ++i)
#pragma unroll
        for (int j = 0; j < 4; ++j)
#pragma unroll
            for (int g = 0; g < 4; ++g) {
                float base = acc[i][j][g] * scale;
                float t = fmaf(base, s_h, epbv);
                float e = (t >= 0.f) ? t : 0.2f * t;
                acc[i][j][g] = base + e;
            }

    float mv[16], sv[16];
#pragma unroll
    for (int i = 0; i < 4; ++i)
#pragma unroll
        for (int g = 0; g < 4; ++g)
            mv[i * 4 + g] = fmaxf(fmaxf(acc[i][0][g], acc[i][1][g]),
                                  fmaxf(acc[i][2][g], acc[i][3][g]));
#pragma unroll
    for (int mask = 1; mask <= 8; mask <<= 1)
#pragma unroll
        for (int t = 0; t < 16; ++t)
            mv[t] = fmaxf(mv[t], __shfl_xor(mv[t], mask));
#pragma unroll
    for (int i = 0; i < 4; ++i)
#pragma unroll
        for (int g = 0; g < 4; ++g) {
            float s = 0.f;
#pragma unroll
            for (int j = 0; j < 4; ++j) s += __expf(acc[i][j][g] - mv[i * 4 + g]);
            sv[i * 4 + g] = s;
        }
#pragma unroll
    for (int mask = 1; mask <= 8; mask <<= 1)
#pragma unroll
        for (int t = 0; t < 16; ++t)
            sv[t] += __shfl_xor(sv[t], mask);

    if (r == 0) {
#pragma unroll
        for (int i = 0; i < 4; ++i)
#pragma unroll
            for (int g = 0; g < 4; ++g) {
                int row = mh + i * 16 + quad * 4 + g;
                mred[wave >> 1][row] = mv[i * 4 + g];
                sred[wave >> 1][row] = sv[i * 4 + g];
            }
    }
    __syncthreads();
    if (tid < 128) {
        float m0 = mred[0][tid], m1 = mred[1][tid];
        float m = fmaxf(m0, m1);
        float s = sred[0][tid] * __expf(m0 - m) + sred[1][tid] * __expf(m1 - m);
        part[(size_t)(p0 >> 7) * (B_ * H_ * S_) + (size_t)bh * S_ + s0 + tid] = make_float2(m, s);
    }
}

// ---------------- fused: rowstats -> recompute QK^T -> normalize -> attn f32 -> PV MFMA ----------------
// 1D grid 2048, XCD-swizzled: the 16 s0-blocks sharing a (bh,split) K/V slice land on one XCD.
// attn written coalesced floatx4 nontemporal from the As f16 tile (identical values PV consumes).
// ctx accumulated via f32 atomicAdd (buffer zeroed in prep).
__global__ __launch_bounds__(256) void attn_pv_kernel(
    const _Float16* __restrict__ Qh, const _Float16* __restrict__ Kh,
    const _Float16* __restrict__ Vt,
    const float* __restrict__ edge_emb, const float* __restrict__ ep_w,
    const float* __restrict__ ep_b, const float2* __restrict__ part,
    float* __restrict__ attn, float* __restrict__ ctx_f32)
{
    __shared__ _Float16 Qs[32 * 72];     // 32 s x 64 k (+8 pad)
    __shared__ _Float16 Ks[128 * 72];    // 128 p x 64 k (+8 pad)
    __shared__ _Float16 Vs[64 * 136];    // 64 d x 128 p (+8 pad)
    __shared__ _Float16 As[32 * 136];    // 32 s x 128 p f16 probs (+8 pad)
    __shared__ float2 ms_sh[32];

    // swizzle: bid = slot + 8*idx; group g = slot + 8*(idx>>4) -> (bh,split); s0i = idx&15.
    int bid = blockIdx.x;
    int slot = bid & 7, idx = bid >> 3;
    int g16 = slot + 8 * (idx >> 4);     // 0..127
    int s0 = (idx & 15) * 32;
    int split = g16 & 7;                 // p-range 512
    int bh = g16 >> 3, h = bh & 7, b = bh >> 3;
    int tid = threadIdx.x;
    int wave = tid >> 6, lane = tid & 63, quad = lane >> 4, r = lane & 15;

    // stage Q once (32 rows x 64 halves = 256 half8, one per thread)
    {
        int row = tid >> 3, ko = (tid & 7) * 8;
        *(half8*)&Qs[row * 72 + ko] =
            *(const half8*)(Qh + (size_t)(b * S_ + s0 + row) * TD_ + h * HD_ + ko);
    }
    // fold rowstats: threads 0..31 each reduce the 32 per-tile partials of one row
    if (tid < 32) {
        int base = bh * S_ + s0 + tid;
        float2 v = part[base];
        float m = v.x, l = v.y;
#pragma unroll
        for (int t = 1; t < 32; ++t) {
            float2 p = part[(size_t)t * (B_ * H_ * S_) + base];
            float nm = fmaxf(m, p.x);
            l = l * __expf(m - nm) + p.y * __expf(p.x - nm);
            m = nm;
        }
        ms_sh[tid] = make_float2(m, 1.0f / l);
    }

    float s_h = 0.f;
#pragma unroll
    for (int e = 0; e < 32; ++e) s_h += edge_emb[h * 32 + e] * ep_w[e];
    float epbv = ep_b[0];

    const _Float16* Kbase = Kh + (size_t)b * P_ * TD_ + h * HD_;   // K[p] at + p*TD_
    const _Float16* Vbase = Vt + (size_t)bh * 64 * P_;             // Vt[d][p] at + d*P_ + p

    int pg0 = split * 512;
    half8 rk[4], rv[4];
#pragma unroll
    for (int ii = 0; ii < 4; ++ii) {
        int e = ii * 256 + tid;
        rk[ii] = *(const half8*)(Kbase + (size_t)(pg0 + (e >> 3)) * TD_ + (e & 7) * 8);
        rv[ii] = *(const half8*)(Vbase + (size_t)(e >> 4) * P_ + pg0 + (e & 15) * 8);
    }

    floatx4 zz = {0.f, 0.f, 0.f, 0.f};
    floatx4 accpv[2];
    accpv[0] = zz; accpv[1] = zz;
    const float scale = 0.125f;

    for (int c = 0; c < 4; ++c) {
        int pg = pg0 + c * 128;
#pragma unroll
        for (int ii = 0; ii < 4; ++ii) {
            int e = ii * 256 + tid;
            *(half8*)&Ks[(e >> 3) * 72 + (e & 7) * 8]  = rk[ii];
            *(half8*)&Vs[(e >> 4) * 136 + (e & 15) * 8] = rv[ii];
        }
        __syncthreads();
        if (c < 3) {
            int pn = pg + 128;
#pragma unroll
            for (int ii = 0; ii < 4; ++ii) {
                int e = ii * 256 + tid;
                rk[ii] = *(const half8*)(Kbase + (size_t)(pn + (e >> 3)) * TD_ + (e & 7) * 8);
                rv[ii] = *(const half8*)(Vbase + (size_t)(e >> 4) * P_ + pn + (e & 15) * 8);
            }
        }

        // QK^T: per wave 32s x 32p (wave owns p sub-range wave*32)
        floatx4 accs[2][2];
        accs[0][0] = zz; accs[0][1] = zz; accs[1][0] = zz; accs[1][1] = zz;
#pragma unroll
        for (int c2 = 0; c2 < 2; ++c2) {
            half8 aq[2], bk2[2];
#pragma unroll
            for (int i = 0; i < 2; ++i)
                aq[i] = *(const half8*)&Qs[(i * 16 + r) * 72 + c2 * 32 + quad * 8];
#pragma unroll
            for (int j = 0; j < 2; ++j)
                bk2[j] = *(const half8*)&Ks[(wave * 32 + j * 16 + r) * 72 + c2 * 32 + quad * 8];
#pragma unroll
            for (int i = 0; i < 2; ++i)
#pragma unroll
                for (int j = 0; j < 2; ++j)
                    accs[i][j] = __builtin_amdgcn_mfma_f32_16x16x32_f16(aq[i], bk2[j], accs[i][j], 0, 0, 0);
        }

        // epilogue: z -> p = exp(z - m) * invl; f16 into As only
#pragma unroll
        for (int i = 0; i < 2; ++i)
#pragma unroll
            for (int j = 0; j < 2; ++j) {
                int colp = wave * 32 + j * 16 + r;
#pragma unroll
                for (int g = 0; g < 4; ++g) {
                    int srow = i * 16 + quad * 4 + g;
                    float base = accs[i][j][g] * scale;
                    float t = fmaf(base, s_h, epbv);
                    float e = (t >= 0.f) ? t : 0.2f * t;
                    float z = base + e;
                    float2 ms = ms_sh[srow];
                    float p = __expf(z - ms.x) * ms.y;
                    As[srow * 136 + colp] = (_Float16)p;
                }
            }
        __syncthreads();   // As visible

        // attn write: coalesced nontemporal floatx4 from As (same f16 values PV uses)
#pragma unroll
        for (int it = 0; it < 4; ++it) {
            int e = it * 256 + tid;
            int row = e >> 5, c4 = (e & 31) * 4;
            half4 hv = *(const half4*)&As[row * 136 + c4];
            floatx4 fv = { (float)hv[0], (float)hv[1], (float)hv[2], (float)hv[3] };
            __builtin_nontemporal_store(fv,
                (floatx4*)&attn[((size_t)bh * S_ + s0 + row) * P_ + pg + c4]);
        }

        // PV: wave owns d in [wave*16, wave*16+16); K = 128 p in 4 chunks of 32
#pragma unroll
        for (int cc = 0; cc < 4; ++cc) {
            half8 bv = *(const half8*)&Vs[(wave * 16 + r) * 136 + cc * 32 + quad * 8];
#pragma unroll
            for (int i2 = 0; i2 < 2; ++i2) {
                half8 ap = *(const half8*)&As[(i2 * 16 + r) * 136 + cc * 32 + quad * 8];
                accpv[i2] = __builtin_amdgcn_mfma_f32_16x16x32_f16(ap, bv, accpv[i2], 0, 0, 0);
            }
        }
        __syncthreads();   // PV done reading Ks/Vs/As before next chunk's ds_write
    }

    // accumulate split partial into ctx (8 splits hit each address)
#pragma unroll
    for (int i2 = 0; i2 < 2; ++i2)
#pragma unroll
        for (int g = 0; g < 4; ++g) {
            int srow = s0 + i2 * 16 + quad * 4 + g;
            int d = wave * 16 + r;
            atomicAdd(&ctx_f32[(size_t)(b * S_ + srow) * TD_ + h * HD_ + d], accpv[i2][g]);
        }
}

extern "C" void kernel_launch(void* const* d_in, const int* in_sizes, int n_in,
                              void* d_out, int out_size, void* d_ws, size_t ws_size,
                              hipStream_t stream) {
    const float* text  = (const float*)d_in[0];
    const float* shape = (const float*)d_in[1];
    const float* tn_g  = (const float*)d_in[2];
    const float* tn_b  = (const float*)d_in[3];
    const float* sn_g  = (const float*)d_in[4];
    const float* sn_b  = (const float*)d_in[5];
    const float* Wq    = (const float*)d_in[6];
    const float* bq    = (const float*)d_in[7];
    const float* Wk    = (const float*)d_in[8];
    const float* bk    = (const float*)d_in[9];
    const float* Wv    = (const float*)d_in[10];
    const float* bv    = (const float*)d_in[11];
    const float* edge  = (const float*)d_in[12];
    const float* epw   = (const float*)d_in[13];
    const float* epb   = (const float*)d_in[14];
    const float* Wo    = (const float*)d_in[15];
    const float* bo    = (const float*)d_in[16];
    const float* on_g  = (const float*)d_in[17];
    const float* on_b  = (const float*)d_in[18];
    const float* W1    = (const float*)d_in[19];
    const float* b1    = (const float*)d_in[20];
    const float* W2    = (const float*)d_in[21];
    const float* b2    = (const float*)d_in[22];
    const float* fn_g  = (const float*)d_in[23];
    const float* fn_b  = (const float*)d_in[24];

    float* out_f  = (float*)d_out;                       // [B,S,TD]
    float* attn_f = out_f + (size_t)B_ * S_ * TD_;       // [B,H,S,P]

    // workspace layout (bytes)
    char* w = (char*)d_ws;
    _Float16* tn_h   = (_Float16*)w; w += (size_t)1024 * 512 * 2;
    _Float16* sn_h   = (_Float16*)w; w += (size_t)8192 * 384 * 2;
    _Float16* Q_h    = (_Float16*)w; w += (size_t)1024 * 512 * 2;
    _Float16* K_h    = (_Float16*)w; w += (size_t)8192 * 512 * 2;
    _Float16* Vt_h   = (_Float16*)w; w += (size_t)16 * 64 * 4096 * 2;
    float*    ctx_f32 = (float*)w;   w += (size_t)1024 * 512 * 4;      // attn ctx accumulator (atomics)
    _Float16* out1_h = (_Float16*)w; w += (size_t)1024 * 512 * 2;
    _Float16* h1_h   = (_Float16*)w; w += (size_t)1024 * 2048 * 2;
    _Float16* Wqt    = (_Float16*)w; w += (size_t)512 * 512 * 2;
    _Float16* Wkt    = (_Float16*)w; w += (size_t)512 * 384 * 2;
    _Float16* Wvt    = (_Float16*)w; w += (size_t)512 * 384 * 2;
    _Float16* Wot    = (_Float16*)w; w += (size_t)512 * 512 * 2;
    _Float16* W1t    = (_Float16*)w; w += (size_t)2048 * 512 * 2;
    _Float16* W2t    = (_Float16*)w; w += (size_t)512 * 2048 * 2;
    float*    out1_f = (float*)w;    w += (size_t)1024 * 512 * 4;
    float*    ctx_part = (float*)w;  w += (size_t)4 * 1024 * 512 * 4;  // 8.4 MB: Wo/FFN2 split-K partials

    // part (2 MB) aliases sn_h (6.29 MB; dead after QKV projections)
    float2* part = (float2*)sn_h;                       // [32][8192]

    // 0+1. weight transposes + both LayerNorms + ctx zero — one launch
    prep_kernel<<<2944 + 1024 + 8192 + 512, 256, 0, stream>>>(
        Wq, Wk, Wv, Wo, W1, W2, Wqt, Wkt, Wvt, Wot, W1t, W2t,
        text, shape, tn_g, tn_b, sn_g, sn_b, tn_h, sn_h, ctx_f32);

    // 2. Q/K/V projections — one launch, 256x128 tiles (V written transposed into Vt)
    qkv_gemm_kernel<<<dim3(4, 68), 512, 0, stream>>>(tn_h, sn_h, Wqt, Wkt, Wvt,
                                                     bq, bk, bv, Q_h, K_h, Vt_h);

    // 3. attention: stats (2048 blocks, XCD-swizzled) -> fused pv (2048 blocks, XCD-swizzled, atomics)
    score_stats_kernel<<<2048, 256, 0, stream>>>(Q_h, K_h, edge, epw, epb, part);
    attn_pv_kernel<<<2048, 256, 0, stream>>>(Q_h, K_h, Vt_h, edge, epw, epb, part, attn_f, ctx_f32);

    // 4. output projection (A = f32 ctx, split-K=4 -> partials) + residual LN (sums partials)
    gemm_f16_kernel<0,1,0,4,1><<<dim3(4, 8, 4), 256, 0, stream>>>(
        (const _Float16*)ctx_f32, Wot, bo, ctx_part, nullptr, 1024, 512, 512);
    ln_add_kernel<<<B_ * S_, 256, 0, stream>>>(text, ctx_part, 4, 1024 * 512, on_g, on_b, out1_f, out1_h);

    // 5. FFN: FFN1 (gelu fused), FFN2 split-K=4 into ctx_part, summed in final LN
    gemm_f16_kernel<1,0,1,1,0><<<dim3(16, 8), 256, 0, stream>>>(out1_h, W1t, b1, nullptr, h1_h, 1024, 2048, 512);
    gemm_f16_kernel<0,1,0,4,0><<<dim3(4, 8, 4), 256, 0, stream>>>(h1_h, W2t, b2, ctx_part, nullptr, 1024, 512, 2048);
    ln_add_kernel<<<B_ * S_, 256, 0, stream>>>(out1_f, ctx_part, 4, 1024 * 512, fn_g, fn_b, out_f, nullptr);
}